// Round 22
// baseline (113.291 us; speedup 1.0000x reference)
//
#include <hip/hip_runtime.h>
#include <hip/hip_bf16.h>
#include <stdint.h>

typedef _Float16 f16;
typedef _Float16 f16x8 __attribute__((ext_vector_type(8)));
typedef __fp16   fp16x2 __attribute__((ext_vector_type(2)));
typedef float    f32x4 __attribute__((ext_vector_type(4)));
typedef float    f32x16 __attribute__((ext_vector_type(16)));

#define GLDS16(g, l) __builtin_amdgcn_global_load_lds(                        \
    (const __attribute__((address_space(1))) void*)(g),                      \
    (__attribute__((address_space(3))) void*)(l), 16, 0, 0)

constexpr int T  = 2048;
constexpr int B  = 2;
constexpr int H  = 16;
constexpr int DM = 1024;
constexpr int MT = B * T;       // 4096 token rows
constexpr int NQKV = 3 * DM;    // 3072
constexpr float QSCALE = 0.125f * 1.4426950408889634f;  // 1/8 * log2(e)

// ------------------------------------------- prep: cast x, weights, tables
__global__ __launch_bounds__(256) void k_prep(const float* __restrict__ x,
        const float* __restrict__ Wq, const float* __restrict__ Wk,
        const float* __restrict__ Wv, const float* __restrict__ Wo,
        f16* __restrict__ xh, f16* __restrict__ WqkvT, f16* __restrict__ WoT,
        float2* __restrict__ tab) {
    const int bid = blockIdx.x, tid = threadIdx.x;
    if (bid < 2048) {
        int i = bid * 256 + tid;
        const float4* p = (const float4*)x;
        float4 a = p[i * 2], b = p[i * 2 + 1];
        f16x8 o = { (f16)a.x, (f16)a.y, (f16)a.z, (f16)a.w,
                    (f16)b.x, (f16)b.y, (f16)b.z, (f16)b.w };
        ((f16x8*)xh)[i] = o;
    } else if (bid < 2304) {
        int idx = (bid - 2048) * 256 + tid;     // T*32
        int t = idx >> 5, f = idx & 31;
        float inv = exp2f(-(float)f * 0.41524101186092034f);
        float ang = (float)t * inv;
        tab[idx] = make_float2(cosf(ang), sinf(ang));
    } else {
        __shared__ float tile[32][33];
        int zz = bid - 2304;                    // 4096 blocks
        int z = zz >> 10, rem = zz & 1023;
        int bx = (rem & 31) * 32, by = (rem >> 5) * 32;
        int tx = tid & 31, ty = tid >> 5;
        const float* src = (z == 0) ? Wq : (z == 1) ? Wk : (z == 2) ? Wv : Wo;
        f16* dst = (z < 3) ? (WqkvT + (size_t)z * DM * DM) : WoT;
        float s = (z == 0) ? QSCALE : 1.f;
#pragma unroll
        for (int j = 0; j < 4; j++)
            tile[ty + j * 8][tx] = src[(size_t)(by + ty + j * 8) * DM + bx + tx];
        __syncthreads();
#pragma unroll
        for (int j = 0; j < 4; j++)
            dst[(size_t)(bx + ty + j * 8) * DM + by + tx] =
                (f16)(tile[tx][ty + j * 8] * s);
    }
}

// --------------------------------- GEMM1 fused with RoPE + head permute
// R21 (verified): 8 waves/block, each wave 32x64.
__global__ __launch_bounds__(512) void k_gemm_qkv(const f16* __restrict__ A,
        const f16* __restrict__ Bt,
        const float* __restrict__ bq, const float* __restrict__ bk,
        const float* __restrict__ bv, const float2* __restrict__ tab,
        f16* __restrict__ QA, f16* __restrict__ KA, f16* __restrict__ VT) {
    __shared__ __align__(16) f16 smem[128 * 128];   // sA | sB, reused as tr
    f16* sA = smem;
    f16* sB = smem + 128 * 64;
    const int tid = threadIdx.x, w = tid >> 6, l = tid & 63;
    const int m0 = blockIdx.x * 128, by = blockIdx.y;
    const int n0 = by * 128;
    const int wm = w >> 1, wn = w & 1;
    const int lrow = tid >> 3;           // 0..63
    const int lch  = tid & 7;
    f32x4 acc[2][4] = {};

    for (int kt = 0; kt < DM; kt += 64) {
        __syncthreads();
#pragma unroll
        for (int i = 0; i < 2; i++) {
            int row = i * 64 + lrow;
            int c = lch ^ (row & 7);
            GLDS16(A + (size_t)(m0 + row) * DM + kt + c * 8, &sA[i * 4096 + w * 512]);
        }
#pragma unroll
        for (int i = 0; i < 2; i++) {
            int row = i * 64 + lrow;
            int c = lch ^ (row & 7);
            GLDS16(Bt + (size_t)(n0 + row) * DM + kt + c * 8, &sB[i * 4096 + w * 512]);
        }
        __syncthreads();
#pragma unroll
        for (int ks = 0; ks < 2; ks++) {
            f16x8 af[2], bf[4];
#pragma unroll
            for (int mi = 0; mi < 2; mi++) {
                int row = wm * 32 + mi * 16 + (l & 15);
                int c = (ks * 4 + (l >> 4)) ^ (row & 7);
                af[mi] = *(const f16x8*)&sA[row * 64 + c * 8];
            }
#pragma unroll
            for (int ni = 0; ni < 4; ni++) {
                int row = wn * 64 + ni * 16 + (l & 15);
                int c = (ks * 4 + (l >> 4)) ^ (row & 7);
                bf[ni] = *(const f16x8*)&sB[row * 64 + c * 8];
            }
#pragma unroll
            for (int ni = 0; ni < 4; ni++)
#pragma unroll
                for (int mi = 0; mi < 2; mi++)
                    acc[mi][ni] = __builtin_amdgcn_mfma_f32_16x16x32_f16(
                        af[mi], bf[ni], acc[mi][ni], 0, 0, 0);
        }
    }

    const int l15 = l & 15, l4 = l >> 4;
    const int bb = m0 >> 11, t0 = m0 & (T - 1);

    if (by < 16) {
        const bool isQ = (by < 8);
        const float* bias = isQ ? bq : bk;
        const float qs = isQ ? QSCALE : 1.f;
        const int nloc = (by & 7) * 128;
        f16* dst = isQ ? QA : KA;
        const int h = (nloc >> 6) + wn;
        f16* hb = dst + ((size_t)(bb * 16 + h) * T) * 64;
#pragma unroll
        for (int ni = 0; ni < 2; ni++) {
            int col1 = nloc + wn * 64 + ni * 16 + l15;
            float b1 = bias[col1] * qs;
            float b2 = bias[col1 + 32] * qs;
            int dh = ni * 16 + l15;
#pragma unroll
            for (int mi = 0; mi < 2; mi++)
#pragma unroll
                for (int r = 0; r < 4; r++) {
                    int t = t0 + wm * 32 + mi * 16 + l4 * 4 + r;
                    float2 cs = tab[(t << 5) + dh];
                    float x1 = acc[mi][ni][r] + b1;
                    float x2 = acc[mi][ni + 2][r] + b2;
                    f16* p = hb + ((size_t)t << 6) + dh;
                    p[0]  = (f16)(x1 * cs.x - x2 * cs.y);
                    p[32] = (f16)(x1 * cs.y + x2 * cs.x);
                }
        }
    } else {
        const int nloc = (by - 16) * 128;
        __syncthreads();
        f16* tr = smem;
#pragma unroll
        for (int ni = 0; ni < 4; ni++) {
            int cl = wn * 64 + ni * 16 + l15;
            float bz = bv[nloc + cl];
#pragma unroll
            for (int mi = 0; mi < 2; mi++)
#pragma unroll
                for (int r = 0; r < 4; r++) {
                    int tl = wm * 32 + mi * 16 + l4 * 4 + r;
                    tr[cl * 128 + (((tl >> 3) ^ (cl & 15)) * 8) + (tl & 7)] =
                        (f16)(acc[mi][ni][r] + bz);
                }
        }
        __syncthreads();
        const int dl0 = tid >> 4, ch = tid & 15;   // dl0 0..31
#pragma unroll
        for (int j = 0; j < 4; j++) {
            int dloc = dl0 + j * 32;
            int vcol = nloc + dloc;
            int h = vcol >> 6, d = vcol & 63;
            f16x8 v = *(const f16x8*)&tr[dloc * 128 + ((ch ^ (dloc & 15)) * 8)];
            *(f16x8*)(VT + ((size_t)(bb * 16 + h) * 64 + d) * T + t0 + ch * 8) = v;
        }
    }
}

// ---------------------------------------------------------------- GEMM2
__global__ __launch_bounds__(512) void k_gemm_out(const f16* __restrict__ A,
                                                  const f16* __restrict__ Bt,
                                                  float* __restrict__ C,
                                                  const float* __restrict__ bias) {
    __shared__ __align__(16) f16 smem[128 * 128];
    f16* sA = smem;
    f16* sB = smem + 128 * 64;
    const int tid = threadIdx.x, w = tid >> 6, l = tid & 63;
    const int m0 = blockIdx.x * 128, n0 = blockIdx.y * 128;
    const int wm = w >> 1, wn = w & 1;
    const int lrow = tid >> 3;
    const int lch  = tid & 7;
    f32x4 acc[2][4] = {};

    for (int kt = 0; kt < DM; kt += 64) {
        __syncthreads();
#pragma unroll
        for (int i = 0; i < 2; i++) {
            int row = i * 64 + lrow;
            int c = lch ^ (row & 7);
            GLDS16(A + (size_t)(m0 + row) * DM + kt + c * 8, &sA[i * 4096 + w * 512]);
        }
#pragma unroll
        for (int i = 0; i < 2; i++) {
            int row = i * 64 + lrow;
            int c = lch ^ (row & 7);
            GLDS16(Bt + (size_t)(n0 + row) * DM + kt + c * 8, &sB[i * 4096 + w * 512]);
        }
        __syncthreads();
#pragma unroll
        for (int ks = 0; ks < 2; ks++) {
            f16x8 af[2], bf[4];
#pragma unroll
            for (int mi = 0; mi < 2; mi++) {
                int row = wm * 32 + mi * 16 + (l & 15);
                int c = (ks * 4 + (l >> 4)) ^ (row & 7);
                af[mi] = *(const f16x8*)&sA[row * 64 + c * 8];
            }
#pragma unroll
            for (int ni = 0; ni < 4; ni++) {
                int row = wn * 64 + ni * 16 + (l & 15);
                int c = (ks * 4 + (l >> 4)) ^ (row & 7);
                bf[ni] = *(const f16x8*)&sB[row * 64 + c * 8];
            }
#pragma unroll
            for (int ni = 0; ni < 4; ni++)
#pragma unroll
                for (int mi = 0; mi < 2; mi++)
                    acc[mi][ni] = __builtin_amdgcn_mfma_f32_16x16x32_f16(
                        af[mi], bf[ni], acc[mi][ni], 0, 0, 0);
        }
    }
    const int rb = m0 + wm * 32 + ((l >> 4) << 2);
    const int cb = n0 + wn * 64 + (l & 15);
#pragma unroll
    for (int ni = 0; ni < 4; ni++) {
        int col = cb + ni * 16;
        float bz = bias[col];
#pragma unroll
        for (int mi = 0; mi < 2; mi++)
#pragma unroll
            for (int r = 0; r < 4; r++)
                C[(size_t)(rb + mi * 16 + r) * DM + col] = acc[mi][ni][r] + bz;
    }
}

// -------------------------------------------------------- flash attention
static __device__ inline void plswap(unsigned &a, unsigned &b) {
    auto r = __builtin_amdgcn_permlane32_swap(a, b, false, false);
    a = (unsigned)r[0]; b = (unsigned)r[1];
}

static __device__ inline unsigned pk16(float a, float b) {
    union { fp16x2 h; unsigned u; } cv;
    cv.h = __builtin_amdgcn_cvt_pkrtz(a, b);
    return cv.u;
}

static __device__ inline float ex2(float x) {
#if __has_builtin(__builtin_amdgcn_exp2f)
    return __builtin_amdgcn_exp2f(x);
#else
    float r;
    asm volatile("v_exp_f32 %0, %1\n\ts_nop 1" : "=v"(r) : "v"(x));
    return r;
#endif
}

static __device__ inline f32x16 zero16() { f32x16 z = {}; return z; }

static __device__ inline int swz(int r) { return (r ^ (r >> 3)) & 7; }

// R22: intra-block KV-split. 8 waves/block: waves 0-3 (grp 0) process KV
// [0,1024), waves 4-7 (grp 1) KV [1024,2048), same 128 q-rows. Each group
// runs the verified R9 KVBLK=64 schedule (idx0/idx1 swizzles, no-max
// softmax) + R14 ones-lacc. Grid 512 -> 2 blocks/CU = 16 waves/CU
// (4/SIMD, 2x). No-max partials are PLAIN SUMS -> merge = one LDS
// roundtrip (33 f32/lane, stride 33 conflict-free) reusing dead K space.
constexpr int NTH = 16;  // 16 tiles of 64 per KV half

__global__ __launch_bounds__(512) void k_attn(const f16* __restrict__ QA,
                                              const f16* __restrict__ KA,
                                              const f16* __restrict__ VT,
                                              f16* __restrict__ CTX) {
    __shared__ __align__(16) f16 smem[32768];   // 64 KB
    // layout: K(grp,buf) = smem + (grp*2+buf)*4096 ; V(grp,buf) = +16384
    const int tid = threadIdx.x, w = tid >> 6, l = tid & 63;
    const int grp = w >> 2, wg = w & 3;
    const int lin = blockIdx.x;                 // 512 blocks
    const int bh = lin & 31, qb = lin >> 5;     // XCD = bh%8: head-local L2
    const int b = bh >> 4, h = bh & 15;
    const size_t qbase = (size_t)bh * T * 64;
    const int q0 = qb * 128 + wg * 32;
    const int kv0 = grp * 1024;
    const int lq = l & 31, hi = l >> 5;
    const int sw0 = swz(lq);

    f16* sK0 = smem + (grp * 2 + 0) * 4096;
    f16* sK1 = smem + (grp * 2 + 1) * 4096;
    f16* sV0 = smem + 16384 + (grp * 2 + 0) * 4096;
    f16* sV1 = smem + 16384 + (grp * 2 + 1) * 4096;

    f16x8 qf[4];
#pragma unroll
    for (int kc = 0; kc < 4; kc++)
        qf[kc] = *(const f16x8*)(QA + qbase + (size_t)(q0 + lq) * 64 + kc * 16 + hi * 8);

    f16x8 ones;
#pragma unroll
    for (int e = 0; e < 8; e++) ones[e] = (f16)1.f;

    int idx0[4], idx1[4];
#pragma unroll
    for (int kc = 0; kc < 4; kc++) {
        int g = kc * 2 + hi;
        idx0[kc] = lq * 64 + ((g ^ sw0) * 8);
        idx1[kc] = (32 + lq) * 64 + ((g ^ sw0 ^ 4) * 8);
    }

    f32x16 octx0 = zero16(), octx1 = zero16(), lacc = zero16();

    const int srow = wg * 2;
    const int lr8 = l >> 3, lc8 = l & 7;
    const int row0 = srow * 8 + lr8, row1 = row0 + 8;
    const int c0 = lc8 ^ swz(row0), c1 = lc8 ^ swz(row1);
    const f16* gK0 = KA + qbase + (size_t)(kv0 + row0) * 64 + c0 * 8;
    const f16* gK1 = KA + qbase + (size_t)(kv0 + row1) * 64 + c1 * 8;
    const f16* gV0 = VT + qbase + (size_t)row0 * T + kv0 + c0 * 8;
    const f16* gV1 = VT + qbase + (size_t)row1 * T + kv0 + c1 * 8;

    GLDS16(gK0, sK0 + srow * 512);
    GLDS16(gK1, sK0 + (srow + 1) * 512);
    GLDS16(gV0, sV0 + srow * 512);
    GLDS16(gV1, sV0 + (srow + 1) * 512);
    gK0 += 4096; gK1 += 4096; gV0 += 64; gV1 += 64;
    __syncthreads();

#define ATT_TILE(SKC, SVC, SKN, SVN, TN)                                      \
    {                                                                         \
        if ((TN) < NTH) {                                                     \
            GLDS16(gK0, SKN + srow * 512);                                    \
            GLDS16(gK1, SKN + (srow + 1) * 512);                              \
            GLDS16(gV0, SVN + srow * 512);                                    \
            GLDS16(gV1, SVN + (srow + 1) * 512);                              \
            gK0 += 4096; gK1 += 4096; gV0 += 64; gV1 += 64;                   \
        }                                                                     \
        f32x16 st0 = {}, st1 = {};                                            \
        _Pragma("unroll")                                                     \
        for (int kc = 0; kc < 4; kc++) {                                      \
            f16x8 kf0 = *(const f16x8*)&SKC[idx0[kc]];                        \
            f16x8 kf1 = *(const f16x8*)&SKC[idx1[kc]];                        \
            st0 = __builtin_amdgcn_mfma_f32_32x32x16_f16(kf0, qf[kc], st0, 0, 0, 0); \
            st1 = __builtin_amdgcn_mfma_f32_32x32x16_f16(kf1, qf[kc], st1, 0, 0, 0); \
        }                                                                     \
        _Pragma("unroll")                                                     \
        for (int r = 0; r < 16; r++) {                                        \
            st0[r] = ex2(st0[r]);                                             \
            st1[r] = ex2(st1[r]);                                             \
        }                                                                     \
        unsigned pw0[8], pw1[8];                                              \
        _Pragma("unroll")                                                     \
        for (int j = 0; j < 8; j++) {                                         \
            int r = 4 * (j >> 1) + 2 * (j & 1);                               \
            pw0[j] = pk16(st0[r], st0[r + 1]);                                \
            pw1[j] = pk16(st1[r], st1[r + 1]);                                \
        }                                                                     \
        _Pragma("unroll")                                                     \
        for (int ks = 0; ks < 4; ks++) {                                      \
            unsigned* pwx = (ks < 2) ? pw0 : pw1;                             \
            const int h4 = (ks & 1) * 4;                                      \
            unsigned m0 = pwx[h4 + 0], m2 = pwx[h4 + 2];                      \
            plswap(m0, m2);                                                   \
            unsigned m1 = pwx[h4 + 1], m3 = pwx[h4 + 3];                      \
            plswap(m1, m3);                                                   \
            union { unsigned u[4]; f16x8 v; } pb;                             \
            pb.u[0] = m0; pb.u[1] = m1; pb.u[2] = m2; pb.u[3] = m3;           \
            f16x8 vf0 = *(const f16x8*)&SVC[idx0[ks]];                        \
            f16x8 vf1 = *(const f16x8*)&SVC[idx1[ks]];                        \
            octx0 = __builtin_amdgcn_mfma_f32_32x32x16_f16(vf0, pb.v, octx0, 0, 0, 0); \
            octx1 = __builtin_amdgcn_mfma_f32_32x32x16_f16(vf1, pb.v, octx1, 0, 0, 0); \
            lacc  = __builtin_amdgcn_mfma_f32_32x32x16_f16(ones, pb.v, lacc, 0, 0, 0); \
        }                                                                     \
        __syncthreads();                                                      \
    }

    for (int t = 0; t < NTH; t += 2) {
        ATT_TILE(sK0, sV0, sK1, sV1, t + 1)
        ATT_TILE(sK1, sV1, sK0, sV0, t + 2)
    }
#undef ATT_TILE

    // ---- merge the two KV halves (plain sums under no-max softmax)
    float* mrg = (float*)smem;     // 33.8 KB < 64 KB; buffers are dead
    if (grp == 1) {
        float* dst = mrg + (size_t)(wg * 64 + l) * 33;
#pragma unroll
        for (int r = 0; r < 16; r++) { dst[r] = octx0[r]; dst[16 + r] = octx1[r]; }
        dst[32] = lacc[0];
    }
    __syncthreads();
    if (grp == 0) {
        const float* src = mrg + (size_t)(wg * 64 + l) * 33;
        float inv = 1.f / (lacc[0] + src[32]);
        f16* crow = CTX + ((size_t)b * T + q0 + lq) * DM + h * 64;
#pragma unroll
        for (int rp = 0; rp < 8; rp++) {
            int r = 2 * rp;
            int d = 8 * (rp >> 1) + 2 * (rp & 1) + 4 * hi;
            *(unsigned*)(crow + d) = pk16((octx0[r] + src[r]) * inv,
                                          (octx0[r + 1] + src[r + 1]) * inv);
            *(unsigned*)(crow + 32 + d) = pk16((octx1[r] + src[16 + r]) * inv,
                                               (octx1[r + 1] + src[16 + r + 1]) * inv);
        }
    }
}

// ---------------------------------------------------------------- launch
extern "C" void kernel_launch(void* const* d_in, const int* in_sizes, int n_in,
                              void* d_out, int out_size, void* d_ws, size_t ws_size,
                              hipStream_t stream) {
    const float* x  = (const float*)d_in[0];
    const float* Wq = (const float*)d_in[1];
    const float* bq = (const float*)d_in[2];
    const float* Wk = (const float*)d_in[3];
    const float* bk = (const float*)d_in[4];
    const float* Wv = (const float*)d_in[5];
    const float* bv = (const float*)d_in[6];
    const float* Wo = (const float*)d_in[7];
    const float* bo = (const float*)d_in[8];

    char* ws = (char*)d_ws;
    f16*    xh    = (f16*)(ws + 0);                    // 8 MB
    f16*    ctx   = (f16*)(ws + 0);                    // reuses xh region
    f16*    WqkvT = (f16*)(ws + ((size_t)8  << 20));   // 6 MB
    f16*    WoT   = (f16*)(ws + ((size_t)14 << 20));   // 2 MB
    f16*    QA    = (f16*)(ws + ((size_t)40 << 20));   // 8 MB
    f16*    KA    = (f16*)(ws + ((size_t)48 << 20));   // 8 MB
    f16*    VT    = (f16*)(ws + ((size_t)56 << 20));   // 8 MB
    float2* tab   = (float2*)(ws + ((size_t)64 << 20)); // 512 KB

    k_prep<<<dim3(6400), dim3(256), 0, stream>>>(
        x, Wq, Wk, Wv, Wo, xh, WqkvT, WoT, tab);
    k_gemm_qkv<<<dim3(MT / 128, NQKV / 128), dim3(512), 0, stream>>>(
        xh, WqkvT, bq, bk, bv, tab, QA, KA, VT);
    k_attn<<<dim3(512), dim3(512), 0, stream>>>(QA, KA, VT, ctx);
    k_gemm_out<<<dim3(MT / 128, DM / 128), dim3(512), 0, stream>>>(
        ctx, WoT, (float*)d_out, bo);
}

// Round 23
// 109.061 us; speedup vs baseline: 1.0388x; 1.0388x over previous
//
#include <hip/hip_runtime.h>
#include <hip/hip_bf16.h>
#include <stdint.h>

typedef _Float16 f16;
typedef _Float16 f16x8 __attribute__((ext_vector_type(8)));
typedef __fp16   fp16x2 __attribute__((ext_vector_type(2)));
typedef float    f32x4 __attribute__((ext_vector_type(4)));
typedef float    f32x16 __attribute__((ext_vector_type(16)));

#define GLDS16(g, l) __builtin_amdgcn_global_load_lds(                        \
    (const __attribute__((address_space(1))) void*)(g),                      \
    (__attribute__((address_space(3))) void*)(l), 16, 0, 0)

constexpr int T  = 2048;
constexpr int B  = 2;
constexpr int H  = 16;
constexpr int DM = 1024;
constexpr int MT = B * T;       // 4096 token rows
constexpr int NQKV = 3 * DM;    // 3072
constexpr float QSCALE = 0.125f * 1.4426950408889634f;  // 1/8 * log2(e)

// ------------------------------------------- prep: cast x, weights, tables
__global__ __launch_bounds__(256) void k_prep(const float* __restrict__ x,
        const float* __restrict__ Wq, const float* __restrict__ Wk,
        const float* __restrict__ Wv, const float* __restrict__ Wo,
        f16* __restrict__ xh, f16* __restrict__ WqkvT, f16* __restrict__ WoT,
        float2* __restrict__ tab) {
    const int bid = blockIdx.x, tid = threadIdx.x;
    if (bid < 2048) {
        int i = bid * 256 + tid;
        const float4* p = (const float4*)x;
        float4 a = p[i * 2], b = p[i * 2 + 1];
        f16x8 o = { (f16)a.x, (f16)a.y, (f16)a.z, (f16)a.w,
                    (f16)b.x, (f16)b.y, (f16)b.z, (f16)b.w };
        ((f16x8*)xh)[i] = o;
    } else if (bid < 2304) {
        int idx = (bid - 2048) * 256 + tid;     // T*32
        int t = idx >> 5, f = idx & 31;
        float inv = exp2f(-(float)f * 0.41524101186092034f);
        float ang = (float)t * inv;
        tab[idx] = make_float2(cosf(ang), sinf(ang));
    } else {
        __shared__ float tile[32][33];
        int zz = bid - 2304;                    // 4096 blocks
        int z = zz >> 10, rem = zz & 1023;
        int bx = (rem & 31) * 32, by = (rem >> 5) * 32;
        int tx = tid & 31, ty = tid >> 5;
        const float* src = (z == 0) ? Wq : (z == 1) ? Wk : (z == 2) ? Wv : Wo;
        f16* dst = (z < 3) ? (WqkvT + (size_t)z * DM * DM) : WoT;
        float s = (z == 0) ? QSCALE : 1.f;
#pragma unroll
        for (int j = 0; j < 4; j++)
            tile[ty + j * 8][tx] = src[(size_t)(by + ty + j * 8) * DM + bx + tx];
        __syncthreads();
#pragma unroll
        for (int j = 0; j < 4; j++)
            dst[(size_t)(bx + ty + j * 8) * DM + by + tx] =
                (f16)(tile[tx][ty + j * 8] * s);
    }
}

// --------------------------------- GEMM1 fused with RoPE + head permute
// R21 (verified): 8 waves/block (512 threads), each wave 32x64.
__global__ __launch_bounds__(512) void k_gemm_qkv(const f16* __restrict__ A,
        const f16* __restrict__ Bt,
        const float* __restrict__ bq, const float* __restrict__ bk,
        const float* __restrict__ bv, const float2* __restrict__ tab,
        f16* __restrict__ QA, f16* __restrict__ KA, f16* __restrict__ VT) {
    __shared__ __align__(16) f16 smem[128 * 128];   // sA | sB, reused as tr
    f16* sA = smem;
    f16* sB = smem + 128 * 64;
    const int tid = threadIdx.x, w = tid >> 6, l = tid & 63;
    const int m0 = blockIdx.x * 128, by = blockIdx.y;
    const int n0 = by * 128;
    const int wm = w >> 1, wn = w & 1;   // wm 0..3 (32-row), wn 0..1 (64-col)
    const int lrow = tid >> 3;           // 0..63
    const int lch  = tid & 7;
    f32x4 acc[2][4] = {};

    for (int kt = 0; kt < DM; kt += 64) {
        __syncthreads();
#pragma unroll
        for (int i = 0; i < 2; i++) {
            int row = i * 64 + lrow;
            int c = lch ^ (row & 7);
            GLDS16(A + (size_t)(m0 + row) * DM + kt + c * 8, &sA[i * 4096 + w * 512]);
        }
#pragma unroll
        for (int i = 0; i < 2; i++) {
            int row = i * 64 + lrow;
            int c = lch ^ (row & 7);
            GLDS16(Bt + (size_t)(n0 + row) * DM + kt + c * 8, &sB[i * 4096 + w * 512]);
        }
        __syncthreads();
#pragma unroll
        for (int ks = 0; ks < 2; ks++) {
            f16x8 af[2], bf[4];
#pragma unroll
            for (int mi = 0; mi < 2; mi++) {
                int row = wm * 32 + mi * 16 + (l & 15);
                int c = (ks * 4 + (l >> 4)) ^ (row & 7);
                af[mi] = *(const f16x8*)&sA[row * 64 + c * 8];
            }
#pragma unroll
            for (int ni = 0; ni < 4; ni++) {
                int row = wn * 64 + ni * 16 + (l & 15);
                int c = (ks * 4 + (l >> 4)) ^ (row & 7);
                bf[ni] = *(const f16x8*)&sB[row * 64 + c * 8];
            }
#pragma unroll
            for (int ni = 0; ni < 4; ni++)
#pragma unroll
                for (int mi = 0; mi < 2; mi++)
                    acc[mi][ni] = __builtin_amdgcn_mfma_f32_16x16x32_f16(
                        af[mi], bf[ni], acc[mi][ni], 0, 0, 0);
        }
    }

    const int l15 = l & 15, l4 = l >> 4;
    const int bb = m0 >> 11, t0 = m0 & (T - 1);

    if (by < 16) {
        const bool isQ = (by < 8);
        const float* bias = isQ ? bq : bk;
        const float qs = isQ ? QSCALE : 1.f;
        const int nloc = (by & 7) * 128;
        f16* dst = isQ ? QA : KA;
        const int h = (nloc >> 6) + wn;
        f16* hb = dst + ((size_t)(bb * 16 + h) * T) * 64;
#pragma unroll
        for (int ni = 0; ni < 2; ni++) {
            int col1 = nloc + wn * 64 + ni * 16 + l15;
            float b1 = bias[col1] * qs;
            float b2 = bias[col1 + 32] * qs;
            int dh = ni * 16 + l15;
#pragma unroll
            for (int mi = 0; mi < 2; mi++)
#pragma unroll
                for (int r = 0; r < 4; r++) {
                    int t = t0 + wm * 32 + mi * 16 + l4 * 4 + r;
                    float2 cs = tab[(t << 5) + dh];
                    float x1 = acc[mi][ni][r] + b1;
                    float x2 = acc[mi][ni + 2][r] + b2;
                    f16* p = hb + ((size_t)t << 6) + dh;
                    p[0]  = (f16)(x1 * cs.x - x2 * cs.y);
                    p[32] = (f16)(x1 * cs.y + x2 * cs.x);
                }
        }
    } else {
        const int nloc = (by - 16) * 128;
        __syncthreads();
        f16* tr = smem;
#pragma unroll
        for (int ni = 0; ni < 4; ni++) {
            int cl = wn * 64 + ni * 16 + l15;
            float bz = bv[nloc + cl];
#pragma unroll
            for (int mi = 0; mi < 2; mi++)
#pragma unroll
                for (int r = 0; r < 4; r++) {
                    int tl = wm * 32 + mi * 16 + l4 * 4 + r;
                    tr[cl * 128 + (((tl >> 3) ^ (cl & 15)) * 8) + (tl & 7)] =
                        (f16)(acc[mi][ni][r] + bz);
                }
        }
        __syncthreads();
        const int dl0 = tid >> 4, ch = tid & 15;   // dl0 0..31
#pragma unroll
        for (int j = 0; j < 4; j++) {
            int dloc = dl0 + j * 32;
            int vcol = nloc + dloc;
            int h = vcol >> 6, d = vcol & 63;
            f16x8 v = *(const f16x8*)&tr[dloc * 128 + ((ch ^ (dloc & 15)) * 8)];
            *(f16x8*)(VT + ((size_t)(bb * 16 + h) * 64 + d) * T + t0 + ch * 8) = v;
        }
    }
}

// ---------------------------------------------------------------- GEMM2
// R21: 8 waves/block (512 threads), each wave 32x64.
__global__ __launch_bounds__(512) void k_gemm_out(const f16* __restrict__ A,
                                                  const f16* __restrict__ Bt,
                                                  float* __restrict__ C,
                                                  const float* __restrict__ bias) {
    __shared__ __align__(16) f16 smem[128 * 128];
    f16* sA = smem;
    f16* sB = smem + 128 * 64;
    const int tid = threadIdx.x, w = tid >> 6, l = tid & 63;
    const int m0 = blockIdx.x * 128, n0 = blockIdx.y * 128;
    const int wm = w >> 1, wn = w & 1;
    const int lrow = tid >> 3;
    const int lch  = tid & 7;
    f32x4 acc[2][4] = {};

    for (int kt = 0; kt < DM; kt += 64) {
        __syncthreads();
#pragma unroll
        for (int i = 0; i < 2; i++) {
            int row = i * 64 + lrow;
            int c = lch ^ (row & 7);
            GLDS16(A + (size_t)(m0 + row) * DM + kt + c * 8, &sA[i * 4096 + w * 512]);
        }
#pragma unroll
        for (int i = 0; i < 2; i++) {
            int row = i * 64 + lrow;
            int c = lch ^ (row & 7);
            GLDS16(Bt + (size_t)(n0 + row) * DM + kt + c * 8, &sB[i * 4096 + w * 512]);
        }
        __syncthreads();
#pragma unroll
        for (int ks = 0; ks < 2; ks++) {
            f16x8 af[2], bf[4];
#pragma unroll
            for (int mi = 0; mi < 2; mi++) {
                int row = wm * 32 + mi * 16 + (l & 15);
                int c = (ks * 4 + (l >> 4)) ^ (row & 7);
                af[mi] = *(const f16x8*)&sA[row * 64 + c * 8];
            }
#pragma unroll
            for (int ni = 0; ni < 4; ni++) {
                int row = wn * 64 + ni * 16 + (l & 15);
                int c = (ks * 4 + (l >> 4)) ^ (row & 7);
                bf[ni] = *(const f16x8*)&sB[row * 64 + c * 8];
            }
#pragma unroll
            for (int ni = 0; ni < 4; ni++)
#pragma unroll
                for (int mi = 0; mi < 2; mi++)
                    acc[mi][ni] = __builtin_amdgcn_mfma_f32_16x16x32_f16(
                        af[mi], bf[ni], acc[mi][ni], 0, 0, 0);
        }
    }
    const int rb = m0 + wm * 32 + ((l >> 4) << 2);
    const int cb = n0 + wn * 64 + (l & 15);
#pragma unroll
    for (int ni = 0; ni < 4; ni++) {
        int col = cb + ni * 16;
        float bz = bias[col];
#pragma unroll
        for (int mi = 0; mi < 2; mi++)
#pragma unroll
            for (int r = 0; r < 4; r++)
                C[(size_t)(rb + mi * 16 + r) * DM + col] = acc[mi][ni][r] + bz;
    }
}

// -------------------------------------------------------- flash attention
static __device__ inline void plswap(unsigned &a, unsigned &b) {
    auto r = __builtin_amdgcn_permlane32_swap(a, b, false, false);
    a = (unsigned)r[0]; b = (unsigned)r[1];
}

static __device__ inline unsigned pk16(float a, float b) {
    union { fp16x2 h; unsigned u; } cv;
    cv.h = __builtin_amdgcn_cvt_pkrtz(a, b);
    return cv.u;
}

static __device__ inline float ex2(float x) {
#if __has_builtin(__builtin_amdgcn_exp2f)
    return __builtin_amdgcn_exp2f(x);
#else
    float r;
    asm volatile("v_exp_f32 %0, %1\n\ts_nop 1" : "=v"(r) : "v"(x));
    return r;
#endif
}

static __device__ inline f32x16 zero16() { f32x16 z = {}; return z; }

static __device__ inline int swz(int r) { return (r ^ (r >> 3)) & 7; }

constexpr int NT2 = T / 128;  // 16 kv tiles of 128

// R21 best-verified (109.2us): QBLK=256 via 8 waves/block, 64KB LDS,
// 16 waves/CU. KVBLK=128, K 3-bit / V 4-bit swizzles (rule #21), no-max
// softmax (R8), ones-MFMA row-sum (R14). Rejected by measurement:
// setprio (R4/R15), KV-split external (R5/R12) & intra-block (R22),
// cross-tile MFMA pipeline (R7), chain-split (R18), XCD swizzle (R13),
// x-cast fusion (R16), KVBLK=64 (R22).
__global__ __launch_bounds__(512) void k_attn(const f16* __restrict__ QA,
                                              const f16* __restrict__ KA,
                                              const f16* __restrict__ VT,
                                              f16* __restrict__ CTX) {
    __shared__ __align__(16) f16 sK[2][128 * 64];   // 16 KB each
    __shared__ __align__(16) f16 sV[2][64 * 128];   // 16 KB each
    const int tid = threadIdx.x, w = tid >> 6, l = tid & 63;
    const int lin = blockIdx.x;                 // 256 blocks
    const int bh = lin & 31, qb = lin >> 5;     // XCD = bh%8: head-local L2
    const int b = bh >> 4, h = bh & 15;
    const size_t qbase = (size_t)bh * T * 64;
    const int q0 = qb * 256 + w * 32;
    const int lq = l & 31, hi = l >> 5;
    const int vsw = lq & 15;

    f16x8 qf[4];
#pragma unroll
    for (int kc = 0; kc < 4; kc++)
        qf[kc] = *(const f16x8*)(QA + qbase + (size_t)(q0 + lq) * 64 + kc * 16 + hi * 8);

    f16x8 ones;
#pragma unroll
    for (int e = 0; e < 8; e++) ones[e] = (f16)1.f;

    int kbase[4], swk[4];
#pragma unroll
    for (int kb = 0; kb < 4; kb++) {
        int row = kb * 32 + lq;
        kbase[kb] = row * 64;
        swk[kb] = swz(row);
    }

    f32x16 octx0 = zero16(), octx1 = zero16(), lacc = zero16();

    const int lr8 = l >> 3, lc8 = l & 7;
    const int l16r = l >> 4, l16c = l & 15;
    const f16* gK[2];
    const f16* gV[2];
#pragma unroll
    for (int j = 0; j < 2; j++) {
        int row = w * 16 + j * 8 + lr8;
        int c = lc8 ^ swz(row);
        gK[j] = KA + qbase + (size_t)row * 64 + c * 8;
        int d = w * 8 + j * 4 + l16r;
        int cv = l16c ^ (d & 15);
        gV[j] = VT + qbase + (size_t)d * T + cv * 8;
    }

#pragma unroll
    for (int j = 0; j < 2; j++) {
        GLDS16(gK[j], &sK[0][(w * 16 + j * 8) * 64]);
        GLDS16(gV[j], &sV[0][(w * 8 + j * 4) * 128]);
        gK[j] += 8192; gV[j] += 128;
    }
    __syncthreads();

#define ATT_TILE(CUR, TN)                                                     \
    {                                                                         \
        if ((TN) < NT2) {                                                     \
            _Pragma("unroll")                                                 \
            for (int j = 0; j < 2; j++) {                                     \
                GLDS16(gK[j], &sK[CUR ^ 1][(w * 16 + j * 8) * 64]);           \
                GLDS16(gV[j], &sV[CUR ^ 1][(w * 8 + j * 4) * 128]);           \
                gK[j] += 8192; gV[j] += 128;                                  \
            }                                                                 \
        }                                                                     \
        f32x16 st[4] = {};                                                    \
        _Pragma("unroll")                                                     \
        for (int kb = 0; kb < 4; kb++) {                                      \
            _Pragma("unroll")                                                 \
            for (int kc = 0; kc < 4; kc++) {                                  \
                f16x8 kf = *(const f16x8*)&sK[CUR][kbase[kb] +                \
                                                   (((kc * 2 + hi) ^ swk[kb]) * 8)]; \
                st[kb] = __builtin_amdgcn_mfma_f32_32x32x16_f16(              \
                    kf, qf[kc], st[kb], 0, 0, 0);                             \
            }                                                                 \
        }                                                                     \
        _Pragma("unroll")                                                     \
        for (int kb = 0; kb < 4; kb++) {                                      \
            _Pragma("unroll")                                                 \
            for (int r = 0; r < 16; r++) st[kb][r] = ex2(st[kb][r]);          \
        }                                                                     \
        unsigned pw[4][8];                                                    \
        _Pragma("unroll")                                                     \
        for (int kb = 0; kb < 4; kb++) {                                      \
            _Pragma("unroll")                                                 \
            for (int j = 0; j < 8; j++) {                                     \
                int r = 4 * (j >> 1) + 2 * (j & 1);                           \
                pw[kb][j] = pk16(st[kb][r], st[kb][r + 1]);                   \
            }                                                                 \
        }                                                                     \
        _Pragma("unroll")                                                     \
        for (int ks = 0; ks < 8; ks++) {                                      \
            const int blk = ks >> 1, h4 = (ks & 1) * 4;                       \
            unsigned m0 = pw[blk][h4 + 0], m2 = pw[blk][h4 + 2];              \
            plswap(m0, m2);                                                   \
            unsigned m1 = pw[blk][h4 + 1], m3 = pw[blk][h4 + 3];              \
            plswap(m1, m3);                                                   \
            union { unsigned u[4]; f16x8 v; } pb;                             \
            pb.u[0] = m0; pb.u[1] = m1; pb.u[2] = m2; pb.u[3] = m3;           \
            int slot = (((ks * 2 + hi) ^ vsw)) * 8;                           \
            f16x8 vf0 = *(const f16x8*)&sV[CUR][lq * 128 + slot];             \
            f16x8 vf1 = *(const f16x8*)&sV[CUR][(32 + lq) * 128 + slot];      \
            octx0 = __builtin_amdgcn_mfma_f32_32x32x16_f16(vf0, pb.v, octx0, 0, 0, 0); \
            octx1 = __builtin_amdgcn_mfma_f32_32x32x16_f16(vf1, pb.v, octx1, 0, 0, 0); \
            lacc  = __builtin_amdgcn_mfma_f32_32x32x16_f16(ones, pb.v, lacc, 0, 0, 0); \
        }                                                                     \
        __syncthreads();                                                      \
    }

    for (int t = 0; t < NT2; t += 2) {
        ATT_TILE(0, t + 1)
        ATT_TILE(1, t + 2)
    }
#undef ATT_TILE

    float inv = 1.f / lacc[0];
    f16* crow = CTX + ((size_t)b * T + q0 + lq) * DM + h * 64;
#pragma unroll
    for (int rp = 0; rp < 8; rp++) {
        int r = 2 * rp;
        int d = 8 * (rp >> 1) + 2 * (rp & 1) + 4 * hi;
        *(unsigned*)(crow + d)      = pk16(octx0[r] * inv, octx0[r + 1] * inv);
        *(unsigned*)(crow + 32 + d) = pk16(octx1[r] * inv, octx1[r + 1] * inv);
    }
}

// ---------------------------------------------------------------- launch
extern "C" void kernel_launch(void* const* d_in, const int* in_sizes, int n_in,
                              void* d_out, int out_size, void* d_ws, size_t ws_size,
                              hipStream_t stream) {
    const float* x  = (const float*)d_in[0];
    const float* Wq = (const float*)d_in[1];
    const float* bq = (const float*)d_in[2];
    const float* Wk = (const float*)d_in[3];
    const float* bk = (const float*)d_in[4];
    const float* Wv = (const float*)d_in[5];
    const float* bv = (const float*)d_in[6];
    const float* Wo = (const float*)d_in[7];
    const float* bo = (const float*)d_in[8];

    char* ws = (char*)d_ws;
    f16*    xh    = (f16*)(ws + 0);                    // 8 MB
    f16*    ctx   = (f16*)(ws + 0);                    // reuses xh region
    f16*    WqkvT = (f16*)(ws + ((size_t)8  << 20));   // 6 MB
    f16*    WoT   = (f16*)(ws + ((size_t)14 << 20));   // 2 MB
    f16*    QA    = (f16*)(ws + ((size_t)40 << 20));   // 8 MB
    f16*    KA    = (f16*)(ws + ((size_t)48 << 20));   // 8 MB
    f16*    VT    = (f16*)(ws + ((size_t)56 << 20));   // 8 MB
    float2* tab   = (float2*)(ws + ((size_t)64 << 20)); // 512 KB

    k_prep<<<dim3(6400), dim3(256), 0, stream>>>(
        x, Wq, Wk, Wv, Wo, xh, WqkvT, WoT, tab);
    k_gemm_qkv<<<dim3(MT / 128, NQKV / 128), dim3(512), 0, stream>>>(
        xh, WqkvT, bq, bk, bv, tab, QA, KA, VT);
    k_attn<<<dim3(256), dim3(512), 0, stream>>>(QA, KA, VT, ctx);
    k_gemm_out<<<dim3(MT / 128, DM / 128), dim3(512), 0, stream>>>(
        ctx, WoT, (float*)d_out, bo);
}